// Round 2
// baseline (420.224 us; speedup 1.0000x reference)
//
#include <hip/hip_runtime.h>

#define IH 4096
#define IW 4096
#define KH 7
#define KW 7
#define OH 4090
#define OW 4090

// Block: 256 threads = 64 (x) × 4 (y). Block tile: 256 wide × 16 tall outputs.
// Thread micro-tile: 4 wide × 4 tall = 16 outputs (16 accs + 10-float row buf
// keeps VGPR under the 84 needed for 6 waves/SIMD — latency hiding was the
// R1 bottleneck: VALUBusy 23%, hbm 21%, occupancy 10.7%).
// Grid: ceil(4090/256)=16 × ceil(4090/16)=256.
__global__ __launch_bounds__(256, 6) void conv7x7_kernel(
    const float* __restrict__ x,
    const float* __restrict__ w,
    const float* __restrict__ bias,
    float* __restrict__ out)
{
    const int tid = threadIdx.x;
    const int tx  = tid & 63;   // 0..63  (x position within block tile)
    const int ty  = tid >> 6;   // 0..3   (y band within block tile)
    const int ox0 = blockIdx.x * 256 + tx * 4;
    const int oy0 = blockIdx.y * 16  + ty * 4;

    // Weights are wave-uniform -> compiler emits s_load, lives in SGPRs.
    float wt[KH * KW];
#pragma unroll
    for (int k = 0; k < KH * KW; ++k) wt[k] = w[k];
    const float b = bias[0];

    float acc[4][4];
#pragma unroll
    for (int r = 0; r < 4; ++r)
#pragma unroll
        for (int c = 0; c < 4; ++c) acc[r][c] = b;

    // Vector path valid when all 10 input columns ox0..ox0+9 are in-bounds.
    const bool xvec = (ox0 + 9) < IW;

#pragma unroll
    for (int ir = 0; ir < 10; ++ir) {
        int iy = oy0 + ir;
        iy = iy < IH ? iy : IH - 1;           // clamp: only affects unstored outputs
        const float* xr = x + (size_t)iy * IW;

        float r[10];
        if (xvec) {
            const float4 q0 = *(const float4*)(xr + ox0);       // 16B aligned
            const float4 q1 = *(const float4*)(xr + ox0 + 4);
            const float2 q2 = *(const float2*)(xr + ox0 + 8);
            r[0] = q0.x; r[1] = q0.y; r[2] = q0.z; r[3] = q0.w;
            r[4] = q1.x; r[5] = q1.y; r[6] = q1.z; r[7] = q1.w;
            r[8] = q2.x; r[9] = q2.y;
        } else {
#pragma unroll
            for (int j = 0; j < 10; ++j) {
                int ix = ox0 + j;
                ix = ix < IW ? ix : IW - 1;   // clamp: only affects unstored outputs
                r[j] = xr[ix];
            }
        }

#pragma unroll
        for (int ky = 0; ky < KH; ++ky) {
            const int ry = ir - ky;           // output row fed by this input row
            if (ry >= 0 && ry < 4) {          // folded at compile time (full unroll)
#pragma unroll
                for (int kx = 0; kx < KW; ++kx) {
                    const float wv = wt[ky * KW + kx];
#pragma unroll
                    for (int c = 0; c < 4; ++c)
                        acc[ry][c] += wv * r[kx + c];
                }
            }
        }
    }

    // Stores: rows of `out` are 4090 floats -> only 8B alignment guaranteed
    // (index oy*4090+ox0 is always even). Use float2 pairs; scalar at right edge.
#pragma unroll
    for (int ry = 0; ry < 4; ++ry) {
        const int oy = oy0 + ry;
        if (oy < OH) {
            float* orow = out + (size_t)oy * OW;
            if (ox0 + 3 < OW) {
                *(float2*)(orow + ox0)     = make_float2(acc[ry][0], acc[ry][1]);
                *(float2*)(orow + ox0 + 2) = make_float2(acc[ry][2], acc[ry][3]);
            } else {
#pragma unroll
                for (int c = 0; c < 4; ++c)
                    if (ox0 + c < OW) orow[ox0 + c] = acc[ry][c];
            }
        }
    }
}

extern "C" void kernel_launch(void* const* d_in, const int* in_sizes, int n_in,
                              void* d_out, int out_size, void* d_ws, size_t ws_size,
                              hipStream_t stream) {
    const float* x    = (const float*)d_in[0];
    const float* w    = (const float*)d_in[1];
    const float* bias = (const float*)d_in[2];
    float* out        = (float*)d_out;

    dim3 grid((OW + 255) / 256, (OH + 15) / 16);   // 16 x 256
    conv7x7_kernel<<<grid, dim3(256), 0, stream>>>(x, w, bias, out);
}

// Round 4
// 160.185 us; speedup vs baseline: 2.6234x; 2.6234x over previous
//
#include <hip/hip_runtime.h>

#define IH 4096
#define IW 4096
#define KH 7
#define KW 7
#define OH 4090
#define OW 4090

typedef float v2f __attribute__((ext_vector_type(2)));   // native vec for nontemporal store

// Thread micro-tile: 8 wide x 4 tall. Block 256 threads = 64(x) x 4(y)
// -> block tile 512 wide x 16 tall. Grid 8 x 256.
// R2 lesson: do NOT force min-occupancy (spilled to scratch, 6x regression).
// R1 lesson: load->use serialization stalls waves; fix with explicit 2-row
// software prefetch (3 rotating row buffers, renamed after full unroll).

__device__ __forceinline__ void load_row(float (&r)[14], const float* __restrict__ x,
                                         int oy0, int ir, int ox0, bool xvec) {
    int iy = oy0 + ir;
    iy = iy < IH ? iy : IH - 1;               // clamp: affects only unstored outputs
    const float* xr = x + (size_t)iy * IW;
    if (xvec) {
        const float4 q0 = *(const float4*)(xr + ox0);        // 32B-aligned base
        const float4 q1 = *(const float4*)(xr + ox0 + 4);
        const float4 q2 = *(const float4*)(xr + ox0 + 8);
        const float2 q3 = *(const float2*)(xr + ox0 + 12);
        r[0]=q0.x; r[1]=q0.y; r[2]=q0.z;  r[3]=q0.w;
        r[4]=q1.x; r[5]=q1.y; r[6]=q1.z;  r[7]=q1.w;
        r[8]=q2.x; r[9]=q2.y; r[10]=q2.z; r[11]=q2.w;
        r[12]=q3.x; r[13]=q3.y;
    } else {
#pragma unroll
        for (int j = 0; j < 14; ++j) {
            int ix = ox0 + j;
            ix = ix < IW ? ix : IW - 1;
            r[j] = xr[ix];
        }
    }
}

__global__ __launch_bounds__(256) void conv7x7_kernel(
    const float* __restrict__ x,
    const float* __restrict__ w,
    const float* __restrict__ bias,
    float* __restrict__ out)
{
    const int tid = threadIdx.x;
    const int tx  = tid & 63;
    const int ty  = tid >> 6;
    const int ox0 = blockIdx.x * 512 + tx * 8;
    const int oy0 = blockIdx.y * 16  + ty * 4;

    // Wave-uniform weights -> SGPRs (R1: SGPR_Count=112 confirms).
    float wt[KH * KW];
#pragma unroll
    for (int k = 0; k < KH * KW; ++k) wt[k] = w[k];
    const float b = bias[0];

    float acc[4][8];
#pragma unroll
    for (int r = 0; r < 4; ++r)
#pragma unroll
        for (int c = 0; c < 8; ++c) acc[r][c] = b;

    const bool xvec = (ox0 + 13) < IW;

    // Software pipeline: rows ir-0..9 feed the 4 output rows; keep 2 rows in flight.
    float r0[14], r1[14], r2[14];
    load_row(r0, x, oy0, 0, ox0, xvec);
    load_row(r1, x, oy0, 1, ox0, xvec);

#pragma unroll
    for (int ir = 0; ir < 10; ++ir) {
        if (ir + 2 < 10)
            load_row(r2, x, oy0, ir + 2, ox0, xvec);   // prefetch 2 ahead

#pragma unroll
        for (int ky = 0; ky < KH; ++ky) {
            const int ry = ir - ky;                    // folded at compile time
            if (ry >= 0 && ry < 4) {
#pragma unroll
                for (int kx = 0; kx < KW; ++kx) {
                    const float wv = wt[ky * KW + kx];
#pragma unroll
                    for (int c = 0; c < 8; ++c)
                        acc[ry][c] += wv * r0[kx + c];
                }
            }
        }

        // rotate buffers (register-renamed after full unroll)
#pragma unroll
        for (int j = 0; j < 14; ++j) { r0[j] = r1[j]; r1[j] = r2[j]; }
    }

    // Stores: out rows are 4090 floats; index oy*4090+ox0 is even -> 8B aligned.
    // Nontemporal: don't let the 67MB write stream evict input halos from L2.
#pragma unroll
    for (int ry = 0; ry < 4; ++ry) {
        const int oy = oy0 + ry;
        if (oy < OH) {
            float* orow = out + (size_t)oy * OW;
            if (ox0 + 7 < OW) {
#pragma unroll
                for (int c = 0; c < 8; c += 2) {
                    v2f v = { acc[ry][c], acc[ry][c + 1] };
                    __builtin_nontemporal_store(v, (v2f*)(orow + ox0 + c));
                }
            } else {
#pragma unroll
                for (int c = 0; c < 8; ++c)
                    if (ox0 + c < OW) orow[ox0 + c] = acc[ry][c];
            }
        }
    }
}

extern "C" void kernel_launch(void* const* d_in, const int* in_sizes, int n_in,
                              void* d_out, int out_size, void* d_ws, size_t ws_size,
                              hipStream_t stream) {
    const float* x    = (const float*)d_in[0];
    const float* w    = (const float*)d_in[1];
    const float* bias = (const float*)d_in[2];
    float* out        = (float*)d_out;

    dim3 grid((OW + 511) / 512, (OH + 15) / 16);   // 8 x 256
    conv7x7_kernel<<<grid, dim3(256), 0, stream>>>(x, w, bias, out);
}

// Round 5
// 144.346 us; speedup vs baseline: 2.9112x; 1.1097x over previous
//
#include <hip/hip_runtime.h>

#define IH 4096
#define IW 4096
#define KH 7
#define KW 7
#define OH 4090
#define OW 4090

#define TW 256            // output tile width  (block)
#define TH 16             // output tile height (block)
#define LW 272            // LDS row stride in floats (covers TW+6=262, 16B multiple)
#define LH (TH + 6)       // 22 input rows staged
#define NV4 (LW / 4)      // 68 float4 per LDS row
#define NLD (LH * NV4)    // 1496 float4 stage loads per block

typedef float v2f __attribute__((ext_vector_type(2)));

// R1/R2/R4 lesson: duration tracked 1/(waves resident); register-resident
// prefetch raises VGPR and kills occupancy. Decouple load from use with LDS:
// all tile loads issued back-to-back (high MLP), one barrier, compute from LDS.
// 23.4 KB LDS -> 6 blocks/CU = 24 waves/CU residency.
__global__ __launch_bounds__(256) void conv7x7_kernel(
    const float* __restrict__ x,
    const float* __restrict__ w,
    const float* __restrict__ bias,
    float* __restrict__ out)
{
    __shared__ float smem[LH * LW];

    const int tid     = threadIdx.x;
    const int tile_x0 = blockIdx.x * TW;
    const int tile_y0 = blockIdx.y * TH;

    // Wave-uniform weights -> SGPRs.
    float wt[KH * KW];
#pragma unroll
    for (int k = 0; k < KH * KW; ++k) wt[k] = w[k];
    const float b = bias[0];

    // ---- Stage: 1496 float4 loads, 6 per thread, all independent ----
#pragma unroll
    for (int i = 0; i < (NLD + 255) / 256; ++i) {
        const int f = tid + i * 256;
        if (f < NLD) {
            const int r  = f / NV4;          // 0..21
            const int c4 = f - r * NV4;      // 0..67
            int iy = tile_y0 + r;
            iy = iy < IH ? iy : IH - 1;      // clamp: feeds only unstored outputs
            const float* xr = x + (size_t)iy * IW;
            const int c0 = tile_x0 + 4 * c4;
            float4 v;
            if (c0 + 3 < IW) {
                v = *(const float4*)(xr + c0);   // 16B aligned, coalesced
            } else {                              // last x-tile edge only
                const int j0 = c0     < IW ? c0     : IW - 1;
                const int j1 = c0 + 1 < IW ? c0 + 1 : IW - 1;
                const int j2 = c0 + 2 < IW ? c0 + 2 : IW - 1;
                const int j3 = c0 + 3 < IW ? c0 + 3 : IW - 1;
                v = make_float4(xr[j0], xr[j1], xr[j2], xr[j3]);
            }
            *(float4*)(&smem[r * LW + 4 * c4]) = v;
        }
    }
    __syncthreads();

    // ---- Compute: thread = 4 wide x 4 tall ----
    const int tx  = tid & 63;                // wave == one y-band
    const int ty  = tid >> 6;                // 0..3
    const int lx0 = 4 * tx;                  // local input col base (16B aligned)

    float acc[4][4];
#pragma unroll
    for (int r = 0; r < 4; ++r)
#pragma unroll
        for (int c = 0; c < 4; ++c) acc[r][c] = b;

#pragma unroll
    for (int ir = 0; ir < TH / 4 * 0 + 10; ++ir) {     // 10 input rows per band
        const float* srow = &smem[(4 * ty + ir) * LW + lx0];
        float rbuf[10];
        const float4 q0 = *(const float4*)(srow);       // lane-contiguous 16B: conflict-free
        const float4 q1 = *(const float4*)(srow + 4);
        const float2 q2 = *(const float2*)(srow + 8);
        rbuf[0]=q0.x; rbuf[1]=q0.y; rbuf[2]=q0.z; rbuf[3]=q0.w;
        rbuf[4]=q1.x; rbuf[5]=q1.y; rbuf[6]=q1.z; rbuf[7]=q1.w;
        rbuf[8]=q2.x; rbuf[9]=q2.y;

#pragma unroll
        for (int ky = 0; ky < KH; ++ky) {
            const int ry = ir - ky;                     // folded at compile time
            if (ry >= 0 && ry < 4) {
#pragma unroll
                for (int kx = 0; kx < KW; ++kx) {
                    const float wv = wt[ky * KW + kx];
#pragma unroll
                    for (int c = 0; c < 4; ++c)
                        acc[ry][c] += wv * rbuf[kx + c];
                }
            }
        }
    }

    // ---- Store: 8B-aligned float2 pairs, nontemporal (don't pollute L2) ----
    const int ox0 = tile_x0 + lx0;
#pragma unroll
    for (int ry = 0; ry < 4; ++ry) {
        const int oy = tile_y0 + 4 * ty + ry;
        if (oy < OH) {
            float* orow = out + (size_t)oy * OW;
            if (ox0 + 3 < OW) {
                v2f v0 = { acc[ry][0], acc[ry][1] };
                v2f v1 = { acc[ry][2], acc[ry][3] };
                __builtin_nontemporal_store(v0, (v2f*)(orow + ox0));
                __builtin_nontemporal_store(v1, (v2f*)(orow + ox0 + 2));
            } else {
#pragma unroll
                for (int c = 0; c < 4; ++c)
                    if (ox0 + c < OW) orow[ox0 + c] = acc[ry][c];
            }
        }
    }
}

extern "C" void kernel_launch(void* const* d_in, const int* in_sizes, int n_in,
                              void* d_out, int out_size, void* d_ws, size_t ws_size,
                              hipStream_t stream) {
    const float* x    = (const float*)d_in[0];
    const float* w    = (const float*)d_in[1];
    const float* bias = (const float*)d_in[2];
    float* out        = (float*)d_out;

    dim3 grid((OW + TW - 1) / TW, (OH + TH - 1) / TH);   // 16 x 256 = 4096 blocks
    conv7x7_kernel<<<grid, dim3(256), 0, stream>>>(x, w, bias, out);
}

// Round 6
// 130.178 us; speedup vs baseline: 3.2281x; 1.1088x over previous
//
#include <hip/hip_runtime.h>
#include <stdint.h>

#define IH 4096
#define IW 4096
#define OH 4090
#define OW 4090

#define TW 256               // output tile width (block)
#define TH 16                // output tile height per step
#define LW 272               // LDS row stride in floats (68 float4 = 1088 B)
#define LH 22                // TH+6 input rows per tile
#define NV4 68               // float4 per LDS row
#define NLD (LH * NV4)       // 1496 float4 per tile stage
#define STEPS 4              // y-tiles per block (sequential, double-buffered)

typedef float v2f __attribute__((ext_vector_type(2)));
typedef __attribute__((address_space(1))) void gas_void;
typedef __attribute__((address_space(3))) void las_void;

// Stage one 262x22 input tile into LDS via global_load_lds (16B, register-free).
// LDS dest is wave-uniform base + lane*16 (m104/m108): our flat-f layout is
// exactly lane-contiguous because NV4*16B == LW*4B (rows butt together).
// Edge handling is ADDRESS clamping (garbage-but-finite values land in LDS
// columns/rows that only feed unstored outputs).
__device__ __forceinline__ void stage_tile(const float* __restrict__ x,
                                           int tile_y0, int tile_x0,
                                           float* sbuf, int tid)
{
    const int wv = tid >> 6;
#pragma unroll
    for (int i = 0; i < (NLD + 255) / 256; ++i) {
        const int f = tid + i * 256;
        if (f < NLD) {
            const int r  = f / NV4;                    // magic-mul, ~3 VALU
            const int c4 = f - r * NV4;
            int iy = tile_y0 + r;
            iy = iy < IH ? iy : IH - 1;                // y clamp
            int c0 = tile_x0 + 4 * c4;
            c0 = c0 <= IW - 4 ? c0 : IW - 4;           // x clamp (keep 16B in-bounds)
            const float* gp = x + (size_t)iy * IW + c0;
            float* lp = sbuf + (size_t)(i * 256 + wv * 64) * 4;   // wave-uniform
            __builtin_amdgcn_global_load_lds((gas_void*)gp, (las_void*)lp, 16, 0, 0);
        }
    }
}

// R5 lesson: b64 at 16B lane stride = 8-way bank conflict -> all LDS reads are
// b128 at 16B lane stride (conflict-free), third read overlaps (floats 8..11).
// R1-R5 lesson: one-shot load->barrier->compute exposes full memory latency;
// double-buffered multi-tile blocks overlap stage(s+1) with compute(s).
__global__ __launch_bounds__(256) void conv7x7_kernel(
    const float* __restrict__ x,
    const float* __restrict__ w,
    const float* __restrict__ bias,
    float* __restrict__ out)
{
    __shared__ float smem[2][LH * LW];                 // 2 x 23.9 KB

    const int tid     = threadIdx.x;
    const int tile_x0 = blockIdx.x * TW;
    const int ytile0  = blockIdx.y * STEPS;

    // Wave-uniform weights -> SGPRs.
    float wt[49];
#pragma unroll
    for (int k = 0; k < 49; ++k) wt[k] = w[k];
    const float b = bias[0];

    stage_tile(x, ytile0 * TH, tile_x0, smem[0], tid);

    const int tx  = tid & 63;
    const int wv  = tid >> 6;
    const int lx0 = 4 * tx;

    for (int s = 0; s < STEPS; ++s) {
        __syncthreads();                               // drains vmcnt: buf[s&1] ready
        if (s + 1 < STEPS)
            stage_tile(x, (ytile0 + s + 1) * TH, tile_x0, smem[(s + 1) & 1], tid);

        const float* sb = smem[s & 1];

        float acc[4][4];
#pragma unroll
        for (int r = 0; r < 4; ++r)
#pragma unroll
            for (int c = 0; c < 4; ++c) acc[r][c] = b;

#pragma unroll
        for (int ir = 0; ir < 10; ++ir) {              // 10 input rows per wave band
            const float* srow = sb + (4 * wv + ir) * LW + lx0;
            const float4 q0 = *(const float4*)(srow);       // b128, conflict-free
            const float4 q1 = *(const float4*)(srow + 4);
            const float4 q2 = *(const float4*)(srow + 8);   // overlapping b128 (was b64: 8-way)
            float rb[12];
            rb[0]=q0.x; rb[1]=q0.y; rb[2]=q0.z;  rb[3]=q0.w;
            rb[4]=q1.x; rb[5]=q1.y; rb[6]=q1.z;  rb[7]=q1.w;
            rb[8]=q2.x; rb[9]=q2.y; rb[10]=q2.z; rb[11]=q2.w;

#pragma unroll
            for (int ky = 0; ky < 7; ++ky) {
                const int ry = ir - ky;                // folded at compile time
                if (ry >= 0 && ry < 4) {
#pragma unroll
                    for (int kx = 0; kx < 7; ++kx) {
                        const float wv_ = wt[ky * 7 + kx];
#pragma unroll
                        for (int c = 0; c < 4; ++c)
                            acc[ry][c] += wv_ * rb[kx + c];
                    }
                }
            }
        }

        // Store: out rows are 4090 floats -> 8B alignment; nontemporal float2.
        const int ox0 = tile_x0 + lx0;
        const int oyb = (ytile0 + s) * TH + 4 * wv;
#pragma unroll
        for (int ry = 0; ry < 4; ++ry) {
            const int oy = oyb + ry;
            if (oy < OH) {
                float* orow = out + (size_t)oy * OW;
                if (ox0 + 3 < OW) {
                    v2f v0 = { acc[ry][0], acc[ry][1] };
                    v2f v1 = { acc[ry][2], acc[ry][3] };
                    __builtin_nontemporal_store(v0, (v2f*)(orow + ox0));
                    __builtin_nontemporal_store(v1, (v2f*)(orow + ox0 + 2));
                } else {
#pragma unroll
                    for (int c = 0; c < 4; ++c)
                        if (ox0 + c < OW) orow[ox0 + c] = acc[ry][c];
                }
            }
        }
    }
}

extern "C" void kernel_launch(void* const* d_in, const int* in_sizes, int n_in,
                              void* d_out, int out_size, void* d_ws, size_t ws_size,
                              hipStream_t stream) {
    const float* x    = (const float*)d_in[0];
    const float* w    = (const float*)d_in[1];
    const float* bias = (const float*)d_in[2];
    float* out        = (float*)d_out;

    // 16 x-tiles, 64 y-groups of 4 tiles -> 1024 blocks (4/CU dispatched,
    // 3 resident by 48KB LDS).
    dim3 grid((OW + TW - 1) / TW, (4096 / TH) / STEPS);
    conv7x7_kernel<<<grid, dim3(256), 0, stream>>>(x, w, bias, out);
}